// Round 2
// 391.541 us; speedup vs baseline: 1.6232x; 1.6232x over previous
//
#include <hip/hip_runtime.h>
#include <stdint.h>

#define N_ROWS 131072
#define DIM 64
#define K_CODES 1024

typedef __attribute__((ext_vector_type(8))) short short8;
typedef __attribute__((ext_vector_type(4))) float float4v;
typedef __attribute__((ext_vector_type(4))) uint32_t u32x4;

__device__ __forceinline__ uint32_t cvt_pk_bf16(float lo, float hi) {
    uint32_t r;
    asm("v_cvt_pk_bf16_f32 %0, %1, %2" : "=v"(r) : "v"(lo), "v"(hi));
    return r;
}
// lo-limb pair: residuals of (fe,fo) against their packed-bf16 word h, repacked to bf16
__device__ __forceinline__ uint32_t lo_pack(float fe, float fo, uint32_t h) {
    float le = fe - __uint_as_float(h << 16);
    float lo_ = fo - __uint_as_float(h & 0xffff0000u);
    return cvt_pk_bf16(le, lo_);
}

// ---------------- kernel 1: per-code squared norms into d_ws ----------------
__global__ __launch_bounds__(256) void sumc2_kernel(const float* __restrict__ cb,
                                                    float* __restrict__ sumc2) {
    int k = blockIdx.x * 256 + threadIdx.x;
    if (k < K_CODES) {
        const float* r = cb + k * DIM;
        float s = 0.f;
        #pragma unroll
        for (int j = 0; j < DIM; ++j) s = fmaf(r[j], r[j], s);
        sumc2[k] = s;
    }
}

// ---------------- threefry2x32 (JAX-compatible, key = (0,42)) ----------------
__device__ __forceinline__ uint32_t rotl32(uint32_t x, uint32_t r) {
    return (x << r) | (x >> (32u - r));
}
__device__ __forceinline__ void tf_round(uint32_t& x0, uint32_t& x1, uint32_t r) {
    x0 += x1; x1 = rotl32(x1, r); x1 ^= x0;
}
__device__ __forceinline__ void threefry2x32_k42(uint32_t c0, uint32_t c1,
                                                 uint32_t& o0, uint32_t& o1) {
    const uint32_t ks0 = 0u, ks1 = 42u, ks2 = 0x1BD11BDAu ^ 0u ^ 42u;
    uint32_t x0 = c0 + ks0, x1 = c1 + ks1;
    tf_round(x0,x1,13); tf_round(x0,x1,15); tf_round(x0,x1,26); tf_round(x0,x1,6);
    x0 += ks1; x1 += ks2 + 1u;
    tf_round(x0,x1,17); tf_round(x0,x1,29); tf_round(x0,x1,16); tf_round(x0,x1,24);
    x0 += ks2; x1 += ks0 + 2u;
    tf_round(x0,x1,13); tf_round(x0,x1,15); tf_round(x0,x1,26); tf_round(x0,x1,6);
    x0 += ks0; x1 += ks1 + 3u;
    tf_round(x0,x1,17); tf_round(x0,x1,29); tf_round(x0,x1,16); tf_round(x0,x1,24);
    x0 += ks1; x1 += ks2 + 4u;
    tf_round(x0,x1,13); tf_round(x0,x1,15); tf_round(x0,x1,26); tf_round(x0,x1,6);
    x0 += ks2; x1 += ks0 + 5u;
    o0 = x0; o1 = x1;
}

// returns v where gumbel = -log(v); v = -log(u) with poly near u->1 (JAX-matching)
__device__ __forceinline__ float gumbel_v(uint32_t bits) {
    uint32_t fb = (bits >> 9) | 0x3f800000u;
    float f = __uint_as_float(fb) - 1.0f;
    float u = fmaxf(1.17549435e-38f, f);
    float w = u - 1.0f;
    float p = fmaf(w, 0.2f, -0.25f);
    p = fmaf(w, p, 0.33333333333f);
    p = fmaf(w, p, -0.5f);
    p = fmaf(w, p, 1.0f);
    float v_poly = -(w * p);
    float v_log  = -__logf(u);
    return (u > 0.9375f) ? v_poly : v_log;
}

// ---------------- kernel 2: fused MFMA quantizer ----------------
// LDS arena (19456 B), two overlaid epochs:
//   epoch A (init only): xhi[4][16][72] @0 (9216), xlo[4][16][72] @9216 (9216)
//   epoch B (main loop): cbhi[32][72] @0 (4608), cblo[32][72] @4608 (4608),
//                        cbT[64][40] @9216 (5120, permuted cols: code i<16 -> 2i,
//                        i>=16 -> 2(i-16)+1), pbuf[4][16][40] @14336 (5120)
// Strides 72/40 halves keep all b128 row bases 16B-aligned.
template<bool T1>
__device__ __forceinline__ void quant_body(
    const float* __restrict__ x, const float* __restrict__ cb,
    const float* __restrict__ sumc2g, const float invT,
    float* __restrict__ out_emb, float* __restrict__ out_ids, char* smem)
{
    uint16_t* const xhiP  = (uint16_t*)smem;           // [4][16][72]
    uint16_t* const xloP  = (uint16_t*)(smem + 9216);  // [4][16][72]
    uint16_t* const cbhiP = (uint16_t*)smem;           // [32][72]
    uint16_t* const cbloP = (uint16_t*)(smem + 4608);  // [32][72]
    uint16_t* const cbTP  = (uint16_t*)(smem + 9216);  // [64][40]
    uint16_t* const pbufP = (uint16_t*)(smem + 14336); // [4][16][40]

    const int tid  = threadIdx.x;
    const int wave = tid >> 6, lane = tid & 63, quad = lane >> 4, col = lane & 15;
    const int rowbase = blockIdx.x * 32 + wave * 8;
    const float twoi = 2.0f * invT;

    // ---- epoch A: stage X tile (bf16 hi + lo residual) ----
    {
        const int s = tid >> 2, w = s >> 4, t = s & 15, dq = tid & 3;
        const int row = blockIdx.x * 32 + w * 8 + (t >> 1) + ((t & 1) << 16);
        const float4* src = reinterpret_cast<const float4*>(x + (size_t)row * DIM + dq * 16);
        float4 f0 = src[0], f1 = src[1], f2 = src[2], f3 = src[3];
        u32x4 hA = { cvt_pk_bf16(f0.x,f0.y), cvt_pk_bf16(f0.z,f0.w),
                     cvt_pk_bf16(f1.x,f1.y), cvt_pk_bf16(f1.z,f1.w) };
        u32x4 hB = { cvt_pk_bf16(f2.x,f2.y), cvt_pk_bf16(f2.z,f2.w),
                     cvt_pk_bf16(f3.x,f3.y), cvt_pk_bf16(f3.z,f3.w) };
        u32x4 lA = { lo_pack(f0.x,f0.y,hA[0]), lo_pack(f0.z,f0.w,hA[1]),
                     lo_pack(f1.x,f1.y,hA[2]), lo_pack(f1.z,f1.w,hA[3]) };
        u32x4 lB = { lo_pack(f2.x,f2.y,hB[0]), lo_pack(f2.z,f2.w,hB[1]),
                     lo_pack(f3.x,f3.y,hB[2]), lo_pack(f3.z,f3.w,hB[3]) };
        uint16_t* dsth = &xhiP[(w*16 + t)*72 + dq*16];
        uint16_t* dstl = &xloP[(w*16 + t)*72 + dq*16];
        *(u32x4*)(dsth)     = hA;
        *(u32x4*)(dsth + 8) = hB;
        *(u32x4*)(dstl)     = lA;
        *(u32x4*)(dstl + 8) = lB;
    }
    __syncthreads();

    // A-frags cached in VGPRs for the whole kernel: A[m=col][k=quad*8+e]
    const int arb = (wave*16 + col)*72;
    const short8 ahi0 = *(const short8*)&xhiP[arb + quad*8];
    const short8 ahi1 = *(const short8*)&xhiP[arb + 32 + quad*8];
    const short8 alo0 = *(const short8*)&xloP[arb + quad*8];
    const short8 alo1 = *(const short8*)&xloP[arb + 32 + quad*8];

    float m[4]  = {-1e30f, -1e30f, -1e30f, -1e30f};
    float Zp[4] = {0.f, 0.f, 0.f, 0.f};
    float4v e0 = {0,0,0,0}, e1 = {0,0,0,0}, e2 = {0,0,0,0}, e3 = {0,0,0,0};
    // top-2 in z-units (z = -dist*invT, so track MAX); ties keep lower k
    float zt[4] = {-3.4e38f,-3.4e38f,-3.4e38f,-3.4e38f};
    float zs[4] = {-3.4e38f,-3.4e38f,-3.4e38f,-3.4e38f};
    int   kt[4] = {0,0,0,0}, ks[4] = {0,0,0,0};

    const uint32_t n0  = (uint32_t)(rowbase + 2*quad);   // < 65536 always
    const uint32_t n1v = n0 + 1u;

    for (int blk = 0; blk < 32; ++blk) {
        const int kb = blk * 32;

        // staging global loads issued before the barrier (no LDS hazard)
        const int scode = tid & 31, sdb = (tid >> 5) * 8;
        const float4* ssrc = reinterpret_cast<const float4*>(cb + (size_t)(kb + scode) * DIM + sdb);
        const float4 sa = ssrc[0], sb = ssrc[1];
        const int kc0 = kb + col, kc1 = kc0 + 16;
        const float sc0 = sumc2g[kc0], sc1 = sumc2g[kc1];

        __syncthreads();                                 // prior tile reads done

        // ---- gumbels (long VALU stretch hides the staging-load latency) ----
        float v0[4], v1[4];
        {
            uint32_t o0, o1, c;
            c = n0 *1024u + (uint32_t)kc0; threefry2x32_k42(c, c + (1u<<26), o0, o1);
            v0[0] = gumbel_v(o0); v0[1] = gumbel_v(o1);
            c = n1v*1024u + (uint32_t)kc0; threefry2x32_k42(c, c + (1u<<26), o0, o1);
            v0[2] = gumbel_v(o0); v0[3] = gumbel_v(o1);
            c = n0 *1024u + (uint32_t)kc1; threefry2x32_k42(c, c + (1u<<26), o0, o1);
            v1[0] = gumbel_v(o0); v1[1] = gumbel_v(o1);
            c = n1v*1024u + (uint32_t)kc1; threefry2x32_k42(c, c + (1u<<26), o0, o1);
            v1[2] = gumbel_v(o0); v1[3] = gumbel_v(o1);
        }
        float r0[4], r1[4];   // T1: 1/v (gumbel folded into softmax); !T1: gumbel log-term
        #pragma unroll
        for (int j = 0; j < 4; ++j) {
            if (T1) { r0[j] = __builtin_amdgcn_rcpf(v0[j]); r1[j] = __builtin_amdgcn_rcpf(v1[j]); }
            else    { r0[j] = -invT * __logf(v0[j]);        r1[j] = -invT * __logf(v1[j]); }
        }

        // ---- staging convert: hi + lo residual rows, permuted cbT scatter (hi) ----
        {
            uint32_t h0 = cvt_pk_bf16(sa.x, sa.y), h1 = cvt_pk_bf16(sa.z, sa.w);
            uint32_t h2 = cvt_pk_bf16(sb.x, sb.y), h3 = cvt_pk_bf16(sb.z, sb.w);
            u32x4 hv = {h0, h1, h2, h3};
            u32x4 lv = { lo_pack(sa.x,sa.y,h0), lo_pack(sa.z,sa.w,h1),
                         lo_pack(sb.x,sb.y,h2), lo_pack(sb.z,sb.w,h3) };
            *(u32x4*)&cbhiP[scode*72 + sdb] = hv;
            *(u32x4*)&cbloP[scode*72 + sdb] = lv;
            const int pc = ((scode & 15) << 1) | (scode >> 4);
            cbTP[(sdb+0)*40 + pc] = (uint16_t)h0;
            cbTP[(sdb+1)*40 + pc] = (uint16_t)(h0 >> 16);
            cbTP[(sdb+2)*40 + pc] = (uint16_t)h1;
            cbTP[(sdb+3)*40 + pc] = (uint16_t)(h1 >> 16);
            cbTP[(sdb+4)*40 + pc] = (uint16_t)h2;
            cbTP[(sdb+5)*40 + pc] = (uint16_t)(h2 >> 16);
            cbTP[(sdb+6)*40 + pc] = (uint16_t)h3;
            cbTP[(sdb+7)*40 + pc] = (uint16_t)(h3 >> 16);
        }
        __syncthreads();

        // ---- GEMM1: S = X . CB^T (split-bf16: hi.hi + hi.lo + lo.hi, 12 MFMA) ----
        float4v S0 = {0,0,0,0}, S1 = {0,0,0,0};
        {
            const int rb0 = col*72;
            const short8 bh0 = *(const short8*)&cbhiP[rb0 + quad*8];
            const short8 bh1 = *(const short8*)&cbhiP[rb0 + 32 + quad*8];
            const short8 bl0 = *(const short8*)&cbloP[rb0 + quad*8];
            const short8 bl1 = *(const short8*)&cbloP[rb0 + 32 + quad*8];
            S0 = __builtin_amdgcn_mfma_f32_16x16x32_bf16(ahi0, bh0, S0, 0,0,0);
            S0 = __builtin_amdgcn_mfma_f32_16x16x32_bf16(ahi1, bh1, S0, 0,0,0);
            S0 = __builtin_amdgcn_mfma_f32_16x16x32_bf16(ahi0, bl0, S0, 0,0,0);
            S0 = __builtin_amdgcn_mfma_f32_16x16x32_bf16(ahi1, bl1, S0, 0,0,0);
            S0 = __builtin_amdgcn_mfma_f32_16x16x32_bf16(alo0, bh0, S0, 0,0,0);
            S0 = __builtin_amdgcn_mfma_f32_16x16x32_bf16(alo1, bh1, S0, 0,0,0);
        }
        {
            const int rb1 = (16 + col)*72;
            const short8 bh0 = *(const short8*)&cbhiP[rb1 + quad*8];
            const short8 bh1 = *(const short8*)&cbhiP[rb1 + 32 + quad*8];
            const short8 bl0 = *(const short8*)&cbloP[rb1 + quad*8];
            const short8 bl1 = *(const short8*)&cbloP[rb1 + 32 + quad*8];
            S1 = __builtin_amdgcn_mfma_f32_16x16x32_bf16(ahi0, bh0, S1, 0,0,0);
            S1 = __builtin_amdgcn_mfma_f32_16x16x32_bf16(ahi1, bh1, S1, 0,0,0);
            S1 = __builtin_amdgcn_mfma_f32_16x16x32_bf16(ahi0, bl0, S1, 0,0,0);
            S1 = __builtin_amdgcn_mfma_f32_16x16x32_bf16(ahi1, bl1, S1, 0,0,0);
            S1 = __builtin_amdgcn_mfma_f32_16x16x32_bf16(alo0, bh0, S1, 0,0,0);
            S1 = __builtin_amdgcn_mfma_f32_16x16x32_bf16(alo1, bh1, S1, 0,0,0);
        }

        // ---- z = -dist*invT (row-constant ||x||^2 dropped: softmax/argmax invariant) ----
        const float nsc0 = -invT * sc0, nsc1 = -invT * sc1;
        float a0[4], a1[4], zm[4];
        #pragma unroll
        for (int j = 0; j < 4; ++j) {
            const float z0 = fmaf(S0[j], twoi, nsc0);
            const float z1 = fmaf(S1[j], twoi, nsc1);
            { const bool c1 = z0 > zt[j], c2 = z0 > zs[j];
              zs[j] = c1 ? zt[j] : (c2 ? z0 : zs[j]);
              ks[j] = c1 ? kt[j] : (c2 ? kc0 : ks[j]);
              zt[j] = c1 ? z0 : zt[j];
              kt[j] = c1 ? kc0 : kt[j]; }
            { const bool c1 = z1 > zt[j], c2 = z1 > zs[j];
              zs[j] = c1 ? zt[j] : (c2 ? z1 : zs[j]);
              ks[j] = c1 ? kt[j] : (c2 ? kc1 : ks[j]);
              zt[j] = c1 ? z1 : zt[j];
              kt[j] = c1 ? kc1 : kt[j]; }
            a0[j] = T1 ? z0 : (z0 + r0[j]);
            a1[j] = T1 ? z1 : (z1 + r1[j]);
            zm[j] = fmaxf(a0[j], a1[j]);
        }

        // ---- deferred max (T13): cross-lane reduce + rescale only on records ----
        bool need;
        if (T1) {
            const float dm = fmaxf(fmaxf(zm[0]-m[0], zm[1]-m[1]), fmaxf(zm[2]-m[2], zm[3]-m[3]));
            need = __any(dm > 11.0f);   // p <= e^11 * 2^23 -- safe in bf16/f32
        } else need = true;
        if (need) {
            float4v av;
            #pragma unroll
            for (int j = 0; j < 4; ++j) {
                float mn = fmaxf(m[j], zm[j]);
                #pragma unroll
                for (int mask = 1; mask < 16; mask <<= 1)
                    mn = fmaxf(mn, __shfl_xor(mn, mask));
                const float al = __expf(m[j] - mn);
                m[j] = mn; Zp[j] *= al; av[j] = al;
            }
            e0 *= av; e1 *= av; e2 *= av; e3 *= av;
        }

        // ---- p = exp(z - m) * (1/v)   (== exp((g - dist)/T - m) exactly for T=1) ----
        #pragma unroll
        for (int j = 0; j < 4; ++j) {
            float p0 = __expf(a0[j] - m[j]);
            float p1 = __expf(a1[j] - m[j]);
            if (T1) { p0 *= r0[j]; p1 *= r1[j]; }
            Zp[j] += p0 + p1;
            ((uint32_t*)pbufP)[(wave*16 + quad*4 + j)*20 + col] = cvt_pk_bf16(p0, p1);
        }

        // ---- GEMM2: emb += P . CB (pbuf is wave-private -> no barrier needed) ----
        const short8 pa  = *(const short8*)&pbufP[(wave*16 + col)*40 + quad*8];
        const short8 bt0 = *(const short8*)&cbTP[( 0 + col)*40 + quad*8];
        const short8 bt1 = *(const short8*)&cbTP[(16 + col)*40 + quad*8];
        const short8 bt2 = *(const short8*)&cbTP[(32 + col)*40 + quad*8];
        const short8 bt3 = *(const short8*)&cbTP[(48 + col)*40 + quad*8];
        e0 = __builtin_amdgcn_mfma_f32_16x16x32_bf16(pa, bt0, e0, 0,0,0);
        e1 = __builtin_amdgcn_mfma_f32_16x16x32_bf16(pa, bt1, e1, 0,0,0);
        e2 = __builtin_amdgcn_mfma_f32_16x16x32_bf16(pa, bt2, e2, 0,0,0);
        e3 = __builtin_amdgcn_mfma_f32_16x16x32_bf16(pa, bt3, e3, 0,0,0);
    }

    // ---- epilogue: reduce Z, merge top-2, f64 refine near-ties, write ----
    #pragma unroll
    for (int mask = 1; mask < 16; mask <<= 1) {
        #pragma unroll
        for (int j = 0; j < 4; ++j) Zp[j] += __shfl_xor(Zp[j], mask);
    }
    #pragma unroll
    for (int mask = 1; mask < 16; mask <<= 1) {
        #pragma unroll
        for (int j = 0; j < 4; ++j) {
            const float ozt = __shfl_xor(zt[j], mask);
            const float ozs = __shfl_xor(zs[j], mask);
            const int   okt = __shfl_xor(kt[j], mask);
            const int   oks = __shfl_xor(ks[j], mask);
            const bool mf = (zt[j] > ozt) || (zt[j] == ozt && kt[j] < okt);
            const float w1 = mf ? zt[j] : ozt;  const int wk1 = mf ? kt[j] : okt;
            const float l1 = mf ? ozt : zt[j];  const int lk1 = mf ? okt : kt[j];
            const float w2 = mf ? zs[j] : ozs;  const int wk2 = mf ? ks[j] : oks;
            const bool s1 = (l1 > w2) || (l1 == w2 && lk1 < wk2);
            zt[j] = w1; kt[j] = wk1;
            zs[j] = s1 ? l1 : w2; ks[j] = s1 ? lk1 : wk2;
        }
    }
    // exact f64 refinement for near-ties (split-bf16 dist err ~1e-6 << 1e-2 margin);
    // gated to col==0 (only the id-writing lane needs it)
    if (col == 0) {
        #pragma unroll
        for (int j = 0; j < 4; ++j) {
            if (zt[j] - zs[j] < 1e-2f * invT) {
                const int t = quad*4 + j;
                const int row = rowbase + (t >> 1) + ((t & 1) << 16);
                const float* xr = x + (size_t)row * DIM;
                const float* cA = cb + (size_t)kt[j] * DIM;
                const float* cB = cb + (size_t)ks[j] * DIM;
                double dA = 0.0, dB = 0.0;     // ||c||^2 - 2 x.c (||x||^2 cancels)
                for (int d = 0; d < DIM; ++d) {
                    const double xv = (double)xr[d];
                    const double av2 = (double)cA[d], bv = (double)cB[d];
                    dA = fma(av2, av2, dA); dA = fma(-2.0*xv, av2, dA);
                    dB = fma(bv,  bv,  dB); dB = fma(-2.0*xv, bv,  dB);
                }
                if (dB < dA || (dB == dA && ks[j] < kt[j])) kt[j] = ks[j];
            }
        }
    }
    #pragma unroll
    for (int j = 0; j < 4; ++j) {
        const int t = quad*4 + j;
        const int row = rowbase + (t >> 1) + ((t & 1) << 16);
        const float rZ = __builtin_amdgcn_rcpf(Zp[j]);
        out_emb[(size_t)row * DIM +      col] = e0[j] * rZ;
        out_emb[(size_t)row * DIM + 16 + col] = e1[j] * rZ;
        out_emb[(size_t)row * DIM + 32 + col] = e2[j] * rZ;
        out_emb[(size_t)row * DIM + 48 + col] = e3[j] * rZ;
        if (col == 0) out_ids[row] = (float)kt[j];
    }
}

__global__ __launch_bounds__(256) __attribute__((amdgpu_waves_per_eu(4, 8)))
void quant_kernel(
    const float* __restrict__ x, const float* __restrict__ cb,
    const float* __restrict__ temp, const float* __restrict__ sumc2g,
    float* __restrict__ out_emb, float* __restrict__ out_ids)
{
    __shared__ __align__(16) char smem[19456];
    const float invT = 1.0f / temp[0];
    if (invT == 1.0f) quant_body<true >(x, cb, sumc2g, invT, out_emb, out_ids, smem);
    else              quant_body<false>(x, cb, sumc2g, invT, out_emb, out_ids, smem);
}

extern "C" void kernel_launch(void* const* d_in, const int* in_sizes, int n_in,
                              void* d_out, int out_size, void* d_ws, size_t ws_size,
                              hipStream_t stream) {
    const float* x    = (const float*)d_in[0];
    const float* cb   = (const float*)d_in[1];
    const float* temp = (const float*)d_in[2];
    float* sumc2      = (float*)d_ws;
    float* out_emb    = (float*)d_out;
    float* out_ids    = (float*)d_out + (size_t)N_ROWS * DIM;

    sumc2_kernel<<<(K_CODES + 255) / 256, 256, 0, stream>>>(cb, sumc2);
    quant_kernel<<<N_ROWS / 64, 256, 0, stream>>>(x, cb, temp, sumc2, out_emb, out_ids);
}

// Round 3
// 361.152 us; speedup vs baseline: 1.7598x; 1.0841x over previous
//
#include <hip/hip_runtime.h>
#include <stdint.h>

#define N_ROWS 131072
#define DIM 64
#define K_CODES 1024

typedef __attribute__((ext_vector_type(8))) short short8;
typedef __attribute__((ext_vector_type(4))) float float4v;
typedef __attribute__((ext_vector_type(4))) uint32_t u32x4;

__device__ __forceinline__ uint32_t cvt_pk_bf16(float lo, float hi) {
    uint32_t r;
    asm("v_cvt_pk_bf16_f32 %0, %1, %2" : "=v"(r) : "v"(lo), "v"(hi));
    return r;
}
// lo-limb pair: residuals of (fe,fo) against their packed-bf16 word h, repacked to bf16
__device__ __forceinline__ uint32_t lo_pack(float fe, float fo, uint32_t h) {
    float le = fe - __uint_as_float(h << 16);
    float lo_ = fo - __uint_as_float(h & 0xffff0000u);
    return cvt_pk_bf16(le, lo_);
}

// async global->LDS DMA, 16B/lane; LDS dest must be wave-uniform base (+lane*16 implicit)
__device__ __forceinline__ void dma16(const void* g, void* l) {
    __builtin_amdgcn_global_load_lds(
        (const __attribute__((address_space(1))) uint32_t*)g,
        (__attribute__((address_space(3))) uint32_t*)l,
        16, 0, 0);
}

template<int V> struct IC { static constexpr int v = V; };

// ---------------- kernel 1: per-code squared norms into d_ws ----------------
__global__ __launch_bounds__(256) void sumc2_kernel(const float* __restrict__ cb,
                                                    float* __restrict__ sumc2) {
    int k = blockIdx.x * 256 + threadIdx.x;
    if (k < K_CODES) {
        const float* r = cb + k * DIM;
        float s = 0.f;
        #pragma unroll
        for (int j = 0; j < DIM; ++j) s = fmaf(r[j], r[j], s);
        sumc2[k] = s;
    }
}

// ---------------- kernel 1b: codebook LDS-image (hi|lo|T-permuted), once ----------------
// Per tile (32 codes): [cbhi 32x72 | cblo 32x72 | cbT 64x40 permuted] = 7168 halves (14336 B).
__global__ __launch_bounds__(256) void cbimg_kernel(const float* __restrict__ cb,
                                                    uint16_t* __restrict__ img) {
    const int tile = blockIdx.x, tid = threadIdx.x;
    const int code = tid & 31, db = (tid >> 5) * 8;
    const int k = tile * 32 + code;
    const float4* src = reinterpret_cast<const float4*>(cb + (size_t)k * DIM + db);
    const float4 a = src[0], b = src[1];
    uint32_t h0 = cvt_pk_bf16(a.x, a.y), h1 = cvt_pk_bf16(a.z, a.w);
    uint32_t h2 = cvt_pk_bf16(b.x, b.y), h3 = cvt_pk_bf16(b.z, b.w);
    u32x4 hv = {h0, h1, h2, h3};
    u32x4 lv = { lo_pack(a.x,a.y,h0), lo_pack(a.z,a.w,h1),
                 lo_pack(b.x,b.y,h2), lo_pack(b.z,b.w,h3) };
    uint16_t* t = img + (size_t)tile * 7168;
    *(u32x4*)&t[code*72 + db]        = hv;
    *(u32x4*)&t[2304 + code*72 + db] = lv;
    const int pc = ((code & 15) << 1) | (code >> 4);
    t[4608 + (db+0)*40 + pc] = (uint16_t)h0;
    t[4608 + (db+1)*40 + pc] = (uint16_t)(h0 >> 16);
    t[4608 + (db+2)*40 + pc] = (uint16_t)h1;
    t[4608 + (db+3)*40 + pc] = (uint16_t)(h1 >> 16);
    t[4608 + (db+4)*40 + pc] = (uint16_t)h2;
    t[4608 + (db+5)*40 + pc] = (uint16_t)(h2 >> 16);
    t[4608 + (db+6)*40 + pc] = (uint16_t)h3;
    t[4608 + (db+7)*40 + pc] = (uint16_t)(h3 >> 16);
}

// ---------------- threefry2x32 (JAX-compatible, key = (0,42)) ----------------
__device__ __forceinline__ uint32_t rotl32(uint32_t x, uint32_t r) {
    return (x << r) | (x >> (32u - r));
}
__device__ __forceinline__ void tf_round(uint32_t& x0, uint32_t& x1, uint32_t r) {
    x0 += x1; x1 = rotl32(x1, r); x1 ^= x0;
}
__device__ __forceinline__ void threefry2x32_k42(uint32_t c0, uint32_t c1,
                                                 uint32_t& o0, uint32_t& o1) {
    const uint32_t ks0 = 0u, ks1 = 42u, ks2 = 0x1BD11BDAu ^ 0u ^ 42u;
    uint32_t x0 = c0 + ks0, x1 = c1 + ks1;
    tf_round(x0,x1,13); tf_round(x0,x1,15); tf_round(x0,x1,26); tf_round(x0,x1,6);
    x0 += ks1; x1 += ks2 + 1u;
    tf_round(x0,x1,17); tf_round(x0,x1,29); tf_round(x0,x1,16); tf_round(x0,x1,24);
    x0 += ks2; x1 += ks0 + 2u;
    tf_round(x0,x1,13); tf_round(x0,x1,15); tf_round(x0,x1,26); tf_round(x0,x1,6);
    x0 += ks0; x1 += ks1 + 3u;
    tf_round(x0,x1,17); tf_round(x0,x1,29); tf_round(x0,x1,16); tf_round(x0,x1,24);
    x0 += ks1; x1 += ks2 + 4u;
    tf_round(x0,x1,13); tf_round(x0,x1,15); tf_round(x0,x1,26); tf_round(x0,x1,6);
    x0 += ks2; x1 += ks0 + 5u;
    o0 = x0; o1 = x1;
}

// returns v where gumbel = -log(v); v = -log(u) with poly near u->1 (JAX-matching)
__device__ __forceinline__ float gumbel_v(uint32_t bits) {
    uint32_t fb = (bits >> 9) | 0x3f800000u;
    float f = __uint_as_float(fb) - 1.0f;
    float u = fmaxf(1.17549435e-38f, f);
    float w = u - 1.0f;
    float p = fmaf(w, 0.2f, -0.25f);
    p = fmaf(w, p, 0.33333333333f);
    p = fmaf(w, p, -0.5f);
    p = fmaf(w, p, 1.0f);
    float v_poly = -(w * p);
    float v_log  = -__logf(u);
    return (u > 0.9375f) ? v_poly : v_log;
}

// ---------------- kernel 2: fused MFMA quantizer ----------------
// LDS arena (33792 B): buf0 @0 (14336), buf1 @14336 (14336), pbuf @28672 (5120).
// Epoch A overlay (dead before first DMA): xhi @0 (9216), xlo @9216 (9216).
// Per-tile buffer layout (halves): cbhi[32][72] @0, cblo @2304, cbT[64][40] @4608
// (cbT cols permuted: code i<16 -> 2i, i>=16 -> 2(i-16)+1).
template<bool T1>
__device__ __forceinline__ void quant_body(
    const float* __restrict__ x, const uint16_t* __restrict__ img,
    const float* __restrict__ cb, const float* __restrict__ sumc2g,
    const float invT, float* __restrict__ out_emb, float* __restrict__ out_ids,
    char* smem)
{
    uint16_t* const xhiP  = (uint16_t*)smem;           // [4][16][72]
    uint16_t* const xloP  = (uint16_t*)(smem + 9216);  // [4][16][72]
    uint16_t* const pbufP = (uint16_t*)(smem + 28672); // [4][16][40]

    const int tid  = threadIdx.x;
    const int wave = tid >> 6, lane = tid & 63, quad = lane >> 4, col = lane & 15;
    const int rowbase = blockIdx.x * 32 + wave * 8;
    const float twoi = 2.0f * invT;

    // ---- epoch A: stage X tile (bf16 hi + lo residual) ----
    {
        const int s = tid >> 2, w = s >> 4, t = s & 15, dq = tid & 3;
        const int row = blockIdx.x * 32 + w * 8 + (t >> 1) + ((t & 1) << 16);
        const float4* src = reinterpret_cast<const float4*>(x + (size_t)row * DIM + dq * 16);
        float4 f0 = src[0], f1 = src[1], f2 = src[2], f3 = src[3];
        u32x4 hA = { cvt_pk_bf16(f0.x,f0.y), cvt_pk_bf16(f0.z,f0.w),
                     cvt_pk_bf16(f1.x,f1.y), cvt_pk_bf16(f1.z,f1.w) };
        u32x4 hB = { cvt_pk_bf16(f2.x,f2.y), cvt_pk_bf16(f2.z,f2.w),
                     cvt_pk_bf16(f3.x,f3.y), cvt_pk_bf16(f3.z,f3.w) };
        u32x4 lA = { lo_pack(f0.x,f0.y,hA[0]), lo_pack(f0.z,f0.w,hA[1]),
                     lo_pack(f1.x,f1.y,hA[2]), lo_pack(f1.z,f1.w,hA[3]) };
        u32x4 lB = { lo_pack(f2.x,f2.y,hB[0]), lo_pack(f2.z,f2.w,hB[1]),
                     lo_pack(f3.x,f3.y,hB[2]), lo_pack(f3.z,f3.w,hB[3]) };
        uint16_t* dsth = &xhiP[(w*16 + t)*72 + dq*16];
        uint16_t* dstl = &xloP[(w*16 + t)*72 + dq*16];
        *(u32x4*)(dsth)     = hA;
        *(u32x4*)(dsth + 8) = hB;
        *(u32x4*)(dstl)     = lA;
        *(u32x4*)(dstl + 8) = lB;
    }
    __syncthreads();

    // A-frags cached in VGPRs for the whole kernel: A[m=col][k=quad*8+e]
    const int arb = (wave*16 + col)*72;
    const short8 ahi0 = *(const short8*)&xhiP[arb + quad*8];
    const short8 ahi1 = *(const short8*)&xhiP[arb + 32 + quad*8];
    const short8 alo0 = *(const short8*)&xloP[arb + quad*8];
    const short8 alo1 = *(const short8*)&xloP[arb + 32 + quad*8];
    __syncthreads();   // all waves done reading xhi/xlo (drained) before DMA overwrites

    // ---- DMA plumbing: wave w copies chunks {w, w+4, w+8, (w+12 if w<2)} of 14 KiB-chunks
    const char* gdma = (const char*)img + (size_t)lane * 16;
    auto dma_tile = [&](int tile, int bofs) {
        const char* s = gdma + (size_t)tile * 14336;
        char* d = smem + bofs;
        dma16(s + (size_t)wave*1024,     d + wave*1024);
        dma16(s + (size_t)(wave+4)*1024, d + (wave+4)*1024);
        dma16(s + (size_t)(wave+8)*1024, d + (wave+8)*1024);
        if (wave < 2) dma16(s + (size_t)(wave+12)*1024, d + (wave+12)*1024);
    };
    dma_tile(0, 0);
    __syncthreads();   // vmcnt(0) drain inside -> tile 0 resident

    float m[4]  = {-1e30f, -1e30f, -1e30f, -1e30f};
    float Zp[4] = {0.f, 0.f, 0.f, 0.f};
    float4v e0 = {0,0,0,0}, e1 = {0,0,0,0}, e2 = {0,0,0,0}, e3 = {0,0,0,0};
    // top-2 in z-units (z = -dist*invT, track MAX); strict > keeps lowest k
    float zt[4] = {-3.4e38f,-3.4e38f,-3.4e38f,-3.4e38f};
    float zs[4] = {-3.4e38f,-3.4e38f,-3.4e38f,-3.4e38f};
    int   kt[4] = {0,0,0,0}, ks[4] = {0,0,0,0};

    // threefry counter base: c(row n0, code kb+col) = base_c0 + kb
    const uint32_t base_c0 = (uint32_t)(rowbase + 2*quad) * 1024u + (uint32_t)col;

    auto body = [&](int blk, auto B) {
        constexpr int BOF = decltype(B)::v;
        const uint16_t* cbhi = (const uint16_t*)(smem + BOF);
        const uint16_t* cblo = cbhi + 2304;
        const uint16_t* cbT  = cbhi + 4608;
        const int kb  = blk * 32;
        const int kc0 = kb + col, kc1 = kc0 + 16;

        if (blk + 1 < 32) dma_tile(blk + 1, BOF ^ 14336);

        const float sc0 = sumc2g[kc0], sc1 = sumc2g[kc1];

        // ---- gumbels (long VALU stretch hides DMA + sc loads) ----
        float v0[4], v1[4];
        {
            uint32_t o0, o1;
            const uint32_t cA = base_c0 + (uint32_t)kb;
            threefry2x32_k42(cA,         cA + (1u<<26),          o0, o1);
            v0[0] = gumbel_v(o0); v0[1] = gumbel_v(o1);
            threefry2x32_k42(cA + 1024u, cA + 1024u + (1u<<26),  o0, o1);
            v0[2] = gumbel_v(o0); v0[3] = gumbel_v(o1);
            threefry2x32_k42(cA + 16u,   cA + 16u + (1u<<26),    o0, o1);
            v1[0] = gumbel_v(o0); v1[1] = gumbel_v(o1);
            threefry2x32_k42(cA + 1040u, cA + 1040u + (1u<<26),  o0, o1);
            v1[2] = gumbel_v(o0); v1[3] = gumbel_v(o1);
        }
        float r0[4], r1[4];  // T1: 1/v (gumbel folded into softmax); !T1: gumbel log-term
        #pragma unroll
        for (int j = 0; j < 4; ++j) {
            if (T1) { r0[j] = __builtin_amdgcn_rcpf(v0[j]); r1[j] = __builtin_amdgcn_rcpf(v1[j]); }
            else    { r0[j] = -invT * __logf(v0[j]);        r1[j] = -invT * __logf(v1[j]); }
        }

        // ---- GEMM1: S = X . CB^T (split-bf16: hi.hi + hi.lo + lo.hi, 12 MFMA) ----
        float4v S0 = {0,0,0,0}, S1 = {0,0,0,0};
        {
            const int rb0 = col*72;
            const short8 bh0 = *(const short8*)&cbhi[rb0 + quad*8];
            const short8 bh1 = *(const short8*)&cbhi[rb0 + 32 + quad*8];
            const short8 bl0 = *(const short8*)&cblo[rb0 + quad*8];
            const short8 bl1 = *(const short8*)&cblo[rb0 + 32 + quad*8];
            S0 = __builtin_amdgcn_mfma_f32_16x16x32_bf16(ahi0, bh0, S0, 0,0,0);
            S0 = __builtin_amdgcn_mfma_f32_16x16x32_bf16(ahi1, bh1, S0, 0,0,0);
            S0 = __builtin_amdgcn_mfma_f32_16x16x32_bf16(ahi0, bl0, S0, 0,0,0);
            S0 = __builtin_amdgcn_mfma_f32_16x16x32_bf16(ahi1, bl1, S0, 0,0,0);
            S0 = __builtin_amdgcn_mfma_f32_16x16x32_bf16(alo0, bh0, S0, 0,0,0);
            S0 = __builtin_amdgcn_mfma_f32_16x16x32_bf16(alo1, bh1, S0, 0,0,0);
        }
        {
            const int rb1 = (16 + col)*72;
            const short8 bh0 = *(const short8*)&cbhi[rb1 + quad*8];
            const short8 bh1 = *(const short8*)&cbhi[rb1 + 32 + quad*8];
            const short8 bl0 = *(const short8*)&cblo[rb1 + quad*8];
            const short8 bl1 = *(const short8*)&cblo[rb1 + 32 + quad*8];
            S1 = __builtin_amdgcn_mfma_f32_16x16x32_bf16(ahi0, bh0, S1, 0,0,0);
            S1 = __builtin_amdgcn_mfma_f32_16x16x32_bf16(ahi1, bh1, S1, 0,0,0);
            S1 = __builtin_amdgcn_mfma_f32_16x16x32_bf16(ahi0, bl0, S1, 0,0,0);
            S1 = __builtin_amdgcn_mfma_f32_16x16x32_bf16(ahi1, bl1, S1, 0,0,0);
            S1 = __builtin_amdgcn_mfma_f32_16x16x32_bf16(alo0, bh0, S1, 0,0,0);
            S1 = __builtin_amdgcn_mfma_f32_16x16x32_bf16(alo1, bh1, S1, 0,0,0);
        }

        // ---- z = -dist*invT (row-constant ||x||^2 dropped) + top-2 via med3 ----
        const float nsc0 = -invT * sc0, nsc1 = -invT * sc1;
        float a0[4], a1[4], zm[4];
        #pragma unroll
        for (int j = 0; j < 4; ++j) {
            const float z0 = fmaf(S0[j], twoi, nsc0);
            const float z1 = fmaf(S1[j], twoi, nsc1);
            {   const bool c1 = z0 > zt[j], c2 = z0 > zs[j];
                const float zsn = __builtin_amdgcn_fmed3f(z0, zt[j], zs[j]);
                ks[j] = c1 ? kt[j] : (c2 ? kc0 : ks[j]);
                kt[j] = c1 ? kc0 : kt[j];
                zt[j] = fmaxf(zt[j], z0);
                zs[j] = zsn; }
            {   const bool c1 = z1 > zt[j], c2 = z1 > zs[j];
                const float zsn = __builtin_amdgcn_fmed3f(z1, zt[j], zs[j]);
                ks[j] = c1 ? kt[j] : (c2 ? kc1 : ks[j]);
                kt[j] = c1 ? kc1 : kt[j];
                zt[j] = fmaxf(zt[j], z1);
                zs[j] = zsn; }
            a0[j] = T1 ? z0 : (z0 + r0[j]);
            a1[j] = T1 ? z1 : (z1 + r1[j]);
            zm[j] = fmaxf(a0[j], a1[j]);
        }

        // ---- deferred max (T13): cross-lane reduce + rescale only on records ----
        bool need;
        if (T1) {
            const float dm = fmaxf(fmaxf(zm[0]-m[0], zm[1]-m[1]), fmaxf(zm[2]-m[2], zm[3]-m[3]));
            need = __any(dm > 11.0f);   // p <= e^11 * 2^23 -- safe in bf16/f32
        } else need = true;
        if (need) {
            float4v av;
            #pragma unroll
            for (int j = 0; j < 4; ++j) {
                float mn = fmaxf(m[j], zm[j]);
                #pragma unroll
                for (int mask = 1; mask < 16; mask <<= 1)
                    mn = fmaxf(mn, __shfl_xor(mn, mask));
                const float al = __expf(m[j] - mn);
                m[j] = mn; Zp[j] *= al; av[j] = al;
            }
            e0 *= av; e1 *= av; e2 *= av; e3 *= av;
        }

        // ---- p = exp(z - m) * (1/v)   (== exp((g - dist)/T - m) exactly for T=1) ----
        #pragma unroll
        for (int j = 0; j < 4; ++j) {
            float p0 = __expf(a0[j] - m[j]);
            float p1 = __expf(a1[j] - m[j]);
            if (T1) { p0 *= r0[j]; p1 *= r1[j]; }
            Zp[j] += p0 + p1;
            ((uint32_t*)pbufP)[(wave*16 + quad*4 + j)*20 + col] = cvt_pk_bf16(p0, p1);
        }

        // ---- GEMM2: emb += P . CB (pbuf is wave-private -> no barrier needed) ----
        const short8 pa  = *(const short8*)&pbufP[(wave*16 + col)*40 + quad*8];
        const short8 bt0 = *(const short8*)&cbT[( 0 + col)*40 + quad*8];
        const short8 bt1 = *(const short8*)&cbT[(16 + col)*40 + quad*8];
        const short8 bt2 = *(const short8*)&cbT[(32 + col)*40 + quad*8];
        const short8 bt3 = *(const short8*)&cbT[(48 + col)*40 + quad*8];
        e0 = __builtin_amdgcn_mfma_f32_16x16x32_bf16(pa, bt0, e0, 0,0,0);
        e1 = __builtin_amdgcn_mfma_f32_16x16x32_bf16(pa, bt1, e1, 0,0,0);
        e2 = __builtin_amdgcn_mfma_f32_16x16x32_bf16(pa, bt2, e2, 0,0,0);
        e3 = __builtin_amdgcn_mfma_f32_16x16x32_bf16(pa, bt3, e3, 0,0,0);

        __syncthreads();   // drains vmcnt (next-tile DMA done) + lgkm; buffers swap-safe
    };

    for (int blk = 0; blk < 32; blk += 2) {
        body(blk,     IC<0>{});
        body(blk + 1, IC<14336>{});
    }

    // ---- epilogue: reduce Z, merge top-2, f64 refine near-ties, write ----
    #pragma unroll
    for (int mask = 1; mask < 16; mask <<= 1) {
        #pragma unroll
        for (int j = 0; j < 4; ++j) Zp[j] += __shfl_xor(Zp[j], mask);
    }
    #pragma unroll
    for (int mask = 1; mask < 16; mask <<= 1) {
        #pragma unroll
        for (int j = 0; j < 4; ++j) {
            const float ozt = __shfl_xor(zt[j], mask);
            const float ozs = __shfl_xor(zs[j], mask);
            const int   okt = __shfl_xor(kt[j], mask);
            const int   oks = __shfl_xor(ks[j], mask);
            const bool mf = (zt[j] > ozt) || (zt[j] == ozt && kt[j] < okt);
            const float w1 = mf ? zt[j] : ozt;  const int wk1 = mf ? kt[j] : okt;
            const float l1 = mf ? ozt : zt[j];  const int lk1 = mf ? okt : kt[j];
            const float w2 = mf ? zs[j] : ozs;  const int wk2 = mf ? ks[j] : oks;
            const bool s1 = (l1 > w2) || (l1 == w2 && lk1 < wk2);
            zt[j] = w1; kt[j] = wk1;
            zs[j] = s1 ? l1 : w2; ks[j] = s1 ? lk1 : wk2;
        }
    }
    // exact f64 refinement for near-ties (split-bf16 dist err ~1e-6 << 1e-2 margin)
    if (col == 0) {
        #pragma unroll
        for (int j = 0; j < 4; ++j) {
            if (zt[j] - zs[j] < 1e-2f * invT) {
                const int t = quad*4 + j;
                const int row = rowbase + (t >> 1) + ((t & 1) << 16);
                const float* xr = x + (size_t)row * DIM;
                const float* cA = cb + (size_t)kt[j] * DIM;
                const float* cB = cb + (size_t)ks[j] * DIM;
                double dA = 0.0, dB = 0.0;     // ||c||^2 - 2 x.c (||x||^2 cancels)
                for (int d = 0; d < DIM; ++d) {
                    const double xv = (double)xr[d];
                    const double av2 = (double)cA[d], bv = (double)cB[d];
                    dA = fma(av2, av2, dA); dA = fma(-2.0*xv, av2, dA);
                    dB = fma(bv,  bv,  dB); dB = fma(-2.0*xv, bv,  dB);
                }
                if (dB < dA || (dB == dA && ks[j] < kt[j])) kt[j] = ks[j];
            }
        }
    }
    #pragma unroll
    for (int j = 0; j < 4; ++j) {
        const int t = quad*4 + j;
        const int row = rowbase + (t >> 1) + ((t & 1) << 16);
        const float rZ = __builtin_amdgcn_rcpf(Zp[j]);
        out_emb[(size_t)row * DIM +      col] = e0[j] * rZ;
        out_emb[(size_t)row * DIM + 16 + col] = e1[j] * rZ;
        out_emb[(size_t)row * DIM + 32 + col] = e2[j] * rZ;
        out_emb[(size_t)row * DIM + 48 + col] = e3[j] * rZ;
        if (col == 0) out_ids[row] = (float)kt[j];
    }
}

__global__ __launch_bounds__(256) __attribute__((amdgpu_waves_per_eu(4)))
void quant_kernel(
    const float* __restrict__ x, const uint16_t* __restrict__ img,
    const float* __restrict__ cb, const float* __restrict__ temp,
    const float* __restrict__ sumc2g,
    float* __restrict__ out_emb, float* __restrict__ out_ids)
{
    __shared__ __align__(16) char smem[33792];
    const float invT = 1.0f / temp[0];
    if (invT == 1.0f) quant_body<true >(x, img, cb, sumc2g, invT, out_emb, out_ids, smem);
    else              quant_body<false>(x, img, cb, sumc2g, invT, out_emb, out_ids, smem);
}

extern "C" void kernel_launch(void* const* d_in, const int* in_sizes, int n_in,
                              void* d_out, int out_size, void* d_ws, size_t ws_size,
                              hipStream_t stream) {
    const float* x    = (const float*)d_in[0];
    const float* cb   = (const float*)d_in[1];
    const float* temp = (const float*)d_in[2];
    float*    sumc2   = (float*)d_ws;
    uint16_t* img     = (uint16_t*)((char*)d_ws + 4096);   // 32 tiles x 14336 B = 448 KiB
    float* out_emb    = (float*)d_out;
    float* out_ids    = (float*)d_out + (size_t)N_ROWS * DIM;

    sumc2_kernel<<<(K_CODES + 255) / 256, 256, 0, stream>>>(cb, sumc2);
    cbimg_kernel<<<32, 256, 0, stream>>>(cb, img);
    quant_kernel<<<N_ROWS / 64, 256, 0, stream>>>(x, img, cb, temp, sumc2, out_emb, out_ids);
}